// Round 12
// baseline (305467.529 us; speedup 1.0000x reference)
//
#include <hip/hip_runtime.h>

typedef __attribute__((ext_vector_type(8))) short bf16x8;
typedef __attribute__((ext_vector_type(4))) float f32x4;

// ---- sizes ----
// B=128, T=256, EMB=512, H=1024, 4H=4096, VOC=32000
// out layout: [128][256][1024] f32, then hT [128][1024], then cT [128][1024]

__device__ __forceinline__ unsigned short f2bf(float f) {
  unsigned int u = __builtin_bit_cast(unsigned int, f);
  u = (u + 0x7FFFu + ((u >> 16) & 1u)) >> 16;  // RNE
  return (unsigned short)u;
}
__device__ __forceinline__ float bf2f(unsigned short s) {
  unsigned int u = ((unsigned int)s) << 16;
  return __builtin_bit_cast(float, u);
}
__device__ __forceinline__ void gload_lds16(const void* g, void* l) {
  __builtin_amdgcn_global_load_lds(
      (const __attribute__((address_space(1))) void*)g,
      (__attribute__((address_space(3))) void*)l, 16, 0, 0);
}
__device__ __forceinline__ float sigm(float x) { return 1.0f / (1.0f + __expf(-x)); }
__device__ __forceinline__ float tanh_f(float x) {
  float e = __expf(2.0f * x);
  return 1.0f - 2.0f / (e + 1.0f);  // saturates correctly, no NaN at +-inf
}

// device-coherent (agent-scope) 16B h load as two 8B atomic loads -- PROVEN path
__device__ __forceinline__ bf16x8 loadh16(const unsigned short* p) {
  unsigned long long* q = (unsigned long long*)p;
  unsigned long long lo = __hip_atomic_load(q, __ATOMIC_RELAXED, __HIP_MEMORY_SCOPE_AGENT);
  unsigned long long hi = __hip_atomic_load(q + 1, __ATOMIC_RELAXED, __HIP_MEMORY_SCOPE_AGENT);
  union { unsigned long long u[2]; bf16x8 v; } c;
  c.u[0] = lo; c.u[1] = hi;
  return c.v;
}

// ---------------- f32 -> bf16 elementwise (emb table) ----------------
__global__ void cvt_bf16_vec(const float4* __restrict__ in, ushort4* __restrict__ out, int n4) {
  int i = blockIdx.x * blockDim.x + threadIdx.x;
  int stride = gridDim.x * blockDim.x;
  for (; i < n4; i += stride) {
    float4 v = in[i];
    ushort4 o;
    o.x = f2bf(v.x); o.y = f2bf(v.y); o.z = f2bf(v.z); o.w = f2bf(v.w);
    out[i] = o;
  }
}

// ---- transpose f32 [K][N] -> bf16 [N][K]; SWZ: bake 16B-slot XOR swizzle ----
template <int SWZ>
__global__ void transpose_cvt(const float* __restrict__ in, unsigned short* __restrict__ out,
                              int K, int N) {
  __shared__ float tile[64][65];
  int k0 = blockIdx.x * 64, n0 = blockIdx.y * 64;
  int tid = threadIdx.x;
  int c = tid & 63, rq = tid >> 6;
#pragma unroll
  for (int rr = 0; rr < 16; ++rr) {
    int r = rr * 4 + rq;
    tile[r][c] = in[(size_t)(k0 + r) * N + n0 + c];
  }
  __syncthreads();
#pragma unroll
  for (int ww = 0; ww < 16; ++ww) {
    int nl = ww * 4 + rq;
    int n = n0 + nl;
    int kd = c;
    int ksrc;
    if (SWZ) {
      int s = kd >> 3, e = kd & 7;
      ksrc = ((((s ^ (n & 7)) & 7)) << 3) | e;
    } else {
      ksrc = kd;
    }
    out[(size_t)n * K + k0 + kd] = f2bf(tile[ksrc][nl]);
  }
}

// ---------------- pre = gather(emb,x) @ W + b   -> bf16 [32768][4096] ----------------
__global__ __launch_bounds__(256) void pregemm(
    const unsigned short* __restrict__ emb_bf, const int* __restrict__ x,
    const unsigned short* __restrict__ W_sw, const float* __restrict__ bias,
    unsigned short* __restrict__ pre) {
  __shared__ __align__(16) unsigned short A_lds[2][8192];  // 128 rows x 64 k (swizzled slots)
  __shared__ __align__(16) unsigned short B_lds[2][8192];
  int bid = blockIdx.x;
  int mtile = bid >> 5, ntile = bid & 31;  // 256 x 32
  int tid = threadIdx.x, wv = tid >> 6, ln = tid & 63;

  int xrow[4];
#pragma unroll
  for (int i = 0; i < 4; ++i) {
    int chunk = wv * 4 + i;
    int r = chunk * 8 + (ln >> 3);
    xrow[i] = x[mtile * 128 + r];
  }

  auto stage = [&](int buf, int kb) {
    int k0 = kb * 64;
#pragma unroll
    for (int i = 0; i < 4; ++i) {
      int chunk = wv * 4 + i;
      int r = chunk * 8 + (ln >> 3);
      const unsigned short* srcA =
          emb_bf + (size_t)xrow[i] * 512 + k0 + (((ln & 7) ^ (r & 7)) << 3);
      gload_lds16(srcA, &A_lds[buf][chunk * 512]);
      const unsigned short* srcB =
          W_sw + (size_t)(ntile * 128 + r) * 512 + k0 + ((ln & 7) << 3);
      gload_lds16(srcB, &B_lds[buf][chunk * 512]);
    }
  };

  f32x4 acc[4][4];
#pragma unroll
  for (int i = 0; i < 4; ++i)
#pragma unroll
    for (int j = 0; j < 4; ++j) acc[i][j] = (f32x4)0.0f;

  int wm = wv >> 1, wn = wv & 1;
  stage(0, 0);
#pragma unroll 1
  for (int kb = 0; kb < 8; ++kb) {
    __syncthreads();
    if (kb < 7) stage((kb + 1) & 1, kb + 1);
    int buf = kb & 1;
#pragma unroll
    for (int ks = 0; ks < 2; ++ks) {
      bf16x8 a[4], b[4];
#pragma unroll
      for (int f = 0; f < 4; ++f) {
        int r = wm * 64 + f * 16 + (ln & 15);
        int sa = ((ks * 4 + (ln >> 4)) ^ (r & 7)) & 7;
        a[f] = *(const bf16x8*)&A_lds[buf][r * 64 + sa * 8];
        int n = wn * 64 + f * 16 + (ln & 15);
        int sb = ((ks * 4 + (ln >> 4)) ^ (n & 7)) & 7;
        b[f] = *(const bf16x8*)&B_lds[buf][n * 64 + sb * 8];
      }
#pragma unroll
      for (int i = 0; i < 4; ++i)
#pragma unroll
        for (int j = 0; j < 4; ++j)
          acc[i][j] = __builtin_amdgcn_mfma_f32_16x16x32_bf16(a[i], b[j], acc[i][j], 0, 0, 0);
    }
  }
#pragma unroll
  for (int fm = 0; fm < 4; ++fm) {
#pragma unroll
    for (int fn = 0; fn < 4; ++fn) {
      int n = ntile * 128 + wn * 64 + fn * 16 + (ln & 15);
      float bn = bias[n];
      int m0 = mtile * 128 + wm * 64 + fm * 16 + ((ln >> 4) << 2);
#pragma unroll
      for (int i = 0; i < 4; ++i) {
        pre[(size_t)(m0 + i) * 4096 + n] = f2bf(acc[fm][fn][i] + bn);
      }
    }
  }
}

// ---------------- init: flags (line-spread) + xcc table ----------------
__global__ void init_sync(unsigned int* flags, unsigned int* xcc) {
  int i = blockIdx.x * blockDim.x + threadIdx.x;  // 4096
  __hip_atomic_store(&flags[i], 0u, __ATOMIC_RELAXED, __HIP_MEMORY_SCOPE_AGENT);
  if (i < 256)
    __hip_atomic_store(&xcc[i], 0xFFFFFFFFu, __ATOMIC_RELAXED, __HIP_MEMORY_SCOPE_AGENT);
}

// ---------------- persistent LSTM recurrence ----------------
// grid 256 = 8 batch-groups x 32 j-slices; bg = bid & 7 so that (under round-robin
// WG->XCD dispatch) all 32 WGs of a bg share one XCD. Protocol = r11 (proven):
// agent (sc1) packed h publish + per-thread vmcnt(0) drain + per-WG line-spread flag;
// per-wave fine poll. NEW: runtime XCD-colocation check (s_getreg XCC_ID published to
// an agent-only table). If this WG's 32 producers are all on my XCD, consume via
// sc0 loads (L1-bypass, L2-hit: producer sc1 stores write through the shared L2) for
// BOTH flags and h. Safety: producers always sc1 (any-scope-safe); sc0 h data is
// bitwise-probed against agent loads at t=1..4 (both parities' first-read and first-
// re-read; mismatch -> permanent agent fallback, probe's agent values used either
// way); sc0 flag poll has timeout -> agent poll. All failure modes = r11 behavior.
__global__ __launch_bounds__(512, 2) void lstm_kernel(
    const unsigned short* __restrict__ pre, const unsigned short* __restrict__ U_t,
    unsigned short* __restrict__ hbc, float* __restrict__ out, unsigned int* flags,
    unsigned int* xccb) {
  __shared__ float zbuf[8][16][132];      // [wave slice][row][z-col], padded
  __shared__ unsigned short hpack[512];   // 16 rows x 32 cols packed h (1 KB)
  int bid = blockIdx.x;
  int bg = bid & 7, js = bid >> 3;        // bg aligned with presumed XCD
  int tid = threadIdx.x, wv = tid >> 6, ln = tid & 63;

  // resident B fragments: ub[gate][kk][cg]; col = gate*1024 + js*32 + cg*16 + (ln&15)
  bf16x8 ub[4][4][2];
#pragma unroll
  for (int g = 0; g < 4; ++g)
#pragma unroll
    for (int kk = 0; kk < 4; ++kk)
#pragma unroll
      for (int cg = 0; cg < 2; ++cg) {
        int col = g * 1024 + js * 32 + cg * 16 + (ln & 15);
        int k = wv * 128 + kk * 32 + ((ln >> 4) << 3);
        ub[g][kk][cg] = *(const bf16x8*)&U_t[(size_t)col * 1024 + k];
      }

  // ---- XCD colocation check (once) ----
  unsigned myxcc;
  asm volatile("s_getreg_b32 %0, hwreg(HW_REG_XCC_ID)" : "=s"(myxcc));
  if (tid == 0)
    __hip_atomic_store(&xccb[bid], myxcc, __ATOMIC_RELAXED, __HIP_MEMORY_SCOPE_AGENT);
  bool colo_f, colo_h;
  {
    int g = 0;
    unsigned v = myxcc;
#pragma unroll 1
    for (;;) {
      v = (ln < 32) ? __hip_atomic_load(&xccb[(ln << 3) + bg], __ATOMIC_RELAXED,
                                        __HIP_MEMORY_SCOPE_AGENT)
                    : myxcc;
      if (__all((int)(v != 0xFFFFFFFFu))) break;
      if (++g > 2000000) break;
      __builtin_amdgcn_s_sleep(1);
    }
    bool same = __all((int)(v == myxcc)) && (g <= 2000000);
    colo_f = same; colo_h = same;
  }

  // gate-phase ownership: 512 threads = 16 rows x 32 j
  int row = tid >> 5, j = tid & 31;
  int b = bg * 16 + row;
  int hcol = js * 32 + j;
  float c_state = 0.0f;
  size_t preb = ((size_t)b * 256) * 4096 + (size_t)(js * 32 + j);
  size_t outb = ((size_t)b * 256) * 1024 + (size_t)hcol;
  int arow = bg * 16 + (ln & 15);
  const unsigned int* flp = flags + ((bg * 32 + (wv << 2) + (ln & 3)) << 4);
  unsigned int* myflag = flags + ((bg * 32 + js) << 4);
  int srow = tid >> 3, sseg = tid & 7;
  size_t hstb = (size_t)(bg * 16 + srow) * 1024 + (size_t)(js * 32 + sseg * 4);

  // prefetch pre[t=0]
  float z0n, z1n, z2n, z3n;
  {
    const unsigned short* pp = pre + preb;
    z0n = bf2f(pp[0]); z1n = bf2f(pp[1024]); z2n = bf2f(pp[2048]); z3n = bf2f(pp[3072]);
  }

#pragma unroll 1
  for (int t = 0; t < 256; ++t) {
    int p = t & 1;
    if (t > 0) {
      // ---- flag wait: sc0 fast poll (L2) with timeout -> proven agent poll ----
      if (colo_f) {
        int g2 = 0;
#pragma unroll 1
        for (;;) {
          unsigned fv;
          asm volatile("global_load_dword %0, %1, off sc0\n\ts_waitcnt vmcnt(0)"
                       : "=v"(fv) : "v"(flp) : "memory");
          if (__all((int)(fv >= (unsigned)t))) break;
          if (++g2 > 300000) { colo_f = false; break; }
          __builtin_amdgcn_s_sleep(1);
        }
      }
      if (!colo_f) {
        int guard = 0;
        while (!__all((int)(__hip_atomic_load(flp, __ATOMIC_RELAXED,
                                              __HIP_MEMORY_SCOPE_AGENT) >= (unsigned)t))) {
          if (++guard > 4000000) break;  // watchdog: fail fast+visibly, never hang
          __builtin_amdgcn_s_sleep(1);
        }
      }
      asm volatile("" ::: "memory");  // no hoisting of h loads above the poll
      const unsigned short* hprev = hbc + (size_t)(p ^ 1) * 131072;
      const unsigned short* hp0 = hprev + (size_t)arow * 1024 + wv * 128 + ((ln >> 4) << 3);
      bf16x8 a[4];
      bool used_sc0 = colo_h;
      if (colo_h) {
        // 4x16B sc0 loads: bypass L1, hit shared-XCD L2 (fresh: producers sc1)
        asm volatile(
            "global_load_dwordx4 %0, %4, off sc0\n\t"
            "global_load_dwordx4 %1, %4, off offset:64 sc0\n\t"
            "global_load_dwordx4 %2, %4, off offset:128 sc0\n\t"
            "global_load_dwordx4 %3, %4, off offset:192 sc0\n\t"
            "s_waitcnt vmcnt(0)"
            : "=&v"(a[0]), "=&v"(a[1]), "=&v"(a[2]), "=&v"(a[3])
            : "v"(hp0)
            : "memory");
      } else {
#pragma unroll
        for (int kk = 0; kk < 4; ++kk) a[kk] = loadh16(hp0 + kk * 32);
      }
      if (used_sc0 && t <= 4) {
        // probe: agent reference must match sc0 data bitwise; use agent values either
        // way (numerics = proven path during the probe window)
        unsigned long long diff = 0ull;
#pragma unroll
        for (int kk = 0; kk < 4; ++kk) {
          bf16x8 r = loadh16(hp0 + kk * 32);
          union { bf16x8 v; unsigned long long u[2]; } ca, cr;
          ca.v = a[kk]; cr.v = r;
          diff |= (ca.u[0] ^ cr.u[0]) | (ca.u[1] ^ cr.u[1]);
          a[kk] = r;
        }
        if (__any((int)(diff != 0ull))) colo_h = false;
      }
      f32x4 acc[4][2];
#pragma unroll
      for (int g = 0; g < 4; ++g)
#pragma unroll
        for (int cg = 0; cg < 2; ++cg) acc[g][cg] = (f32x4)0.0f;
#pragma unroll
      for (int kk = 0; kk < 4; ++kk) {
#pragma unroll
        for (int g = 0; g < 4; ++g)
#pragma unroll
          for (int cg = 0; cg < 2; ++cg)
            acc[g][cg] = __builtin_amdgcn_mfma_f32_16x16x32_bf16(a[kk], ub[g][kk][cg],
                                                                 acc[g][cg], 0, 0, 0);
      }
      // private-slice zbuf writes (conflict-free, r11 layout)
#pragma unroll
      for (int g = 0; g < 4; ++g)
#pragma unroll
        for (int cg = 0; cg < 2; ++cg)
#pragma unroll
          for (int i = 0; i < 4; ++i)
            zbuf[wv][((ln >> 4) << 2) + i][g * 32 + cg * 16 + (ln & 15)] = acc[g][cg][i];
      __syncthreads();  // SYNC1: all z slices visible; joins all waves' polls
    }
    // gates (Keras order i,f,c,o) from prefetched pre values
    float z0 = z0n, z1 = z1n, z2 = z2n, z3 = z3n;
    if (t > 0) {
      float s0 = 0.f, s1 = 0.f, s2 = 0.f, s3 = 0.f;
#pragma unroll
      for (int s = 0; s < 8; ++s) {
        s0 += zbuf[s][row][j];
        s1 += zbuf[s][row][32 + j];
        s2 += zbuf[s][row][64 + j];
        s3 += zbuf[s][row][96 + j];
      }
      z0 += s0; z1 += s1; z2 += s2; z3 += s3;
    }
    float ig = sigm(z0), fg = sigm(z1), gg = tanh_f(z2), og = sigm(z3);
    c_state = fg * c_state + ig * gg;
    float h = og * tanh_f(c_state);
    if (t == 255) {
      out[outb + (size_t)t * 1024] = h;
      out[33554432 + (size_t)b * 1024 + hcol] = h;
      out[33554432 + 131072 + (size_t)b * 1024 + hcol] = c_state;
    } else {
      // packed publish: h -> LDS, then 128 threads issue 8B agent (sc1) stores --
      // ALWAYS sc1: write-through shared L2 + MALL, safe for any consumer scope.
      hpack[row * 32 + j] = f2bf(h);
      __syncthreads();  // SYNC2a: hpack complete (also after all zbuf reads)
      if (tid < 128) {
        unsigned long long v = ((const unsigned long long*)hpack)[tid];
        __hip_atomic_store((unsigned long long*)&hbc[(size_t)p * 131072 + hstb], v,
                           __ATOMIC_RELAXED, __HIP_MEMORY_SCOPE_AGENT);
      }
      // EXPLICIT release drain before the barrier; flag store after it is ordered
      // after all h stores. Also orders zbuf reads(t) vs writes(t+1).
      asm volatile("s_waitcnt vmcnt(0)" ::: "memory");
      __syncthreads();  // SYNC2b
      if (tid == 0)
        __hip_atomic_store(myflag, (unsigned)(t + 1), __ATOMIC_RELAXED,
                           __HIP_MEMORY_SCOPE_AGENT);
      // bulk out store + next-step prefetch AFTER the publish: off the release path
      out[outb + (size_t)t * 1024] = h;
      const unsigned short* pp = pre + preb + (size_t)(t + 1) * 4096;
      z0n = bf2f(pp[0]); z1n = bf2f(pp[1024]); z2n = bf2f(pp[2048]); z3n = bf2f(pp[3072]);
    }
  }
}

// ---------------- launcher ----------------
extern "C" void kernel_launch(void* const* d_in, const int* in_sizes, int n_in,
                              void* d_out, int out_size, void* d_ws, size_t ws_size,
                              hipStream_t stream) {
  const int*   x    = (const int*)d_in[0];
  // d_in[1] = hidden (ignored by reference module)
  const float* emb  = (const float*)d_in[2];
  const float* W    = (const float*)d_in[3];
  const float* U    = (const float*)d_in[4];
  const float* bias = (const float*)d_in[5];
  float* out = (float*)d_out;

  // workspace layout (bytes) -- dedicated agent-only hbc/flags/xcc regions
  const size_t OFS_PRE = 0;                     // 32768*4096*2 = 268435456
  const size_t OFS_EMB = 268435456;             // 32000*512*2  = 32768000
  const size_t OFS_WSW = 301203456;             // 4096*512*2   = 4194304
  const size_t OFS_UT  = 305397760;             // 4096*1024*2  = 8388608
  const size_t OFS_HBC = 313786368;             // 2*128*1024*2 = 524288
  const size_t OFS_FLG = 314310656;             // 256 * 64B    = 16384
  const size_t OFS_XCC = 314327040;             // 256 * 4B     = 1024
  const size_t WS_NEED = 314328064;
  if (ws_size < WS_NEED) return;  // insufficient scratch -> fail validation visibly

  char* ws = (char*)d_ws;
  unsigned short* pre_p = (unsigned short*)(ws + OFS_PRE);
  unsigned short* emb_p = (unsigned short*)(ws + OFS_EMB);
  unsigned short* wsw_p = (unsigned short*)(ws + OFS_WSW);
  unsigned short* ut_p  = (unsigned short*)(ws + OFS_UT);
  unsigned short* hbc_p = (unsigned short*)(ws + OFS_HBC);
  unsigned int*   flg_p = (unsigned int*)(ws + OFS_FLG);
  unsigned int*   xcc_p = (unsigned int*)(ws + OFS_XCC);

  cvt_bf16_vec<<<2048, 256, 0, stream>>>((const float4*)emb, (ushort4*)emb_p, 4096000);
  transpose_cvt<1><<<dim3(8, 64), 256, 0, stream>>>(W, wsw_p, 512, 4096);
  transpose_cvt<0><<<dim3(16, 64), 256, 0, stream>>>(U, ut_p, 1024, 4096);
  init_sync<<<16, 256, 0, stream>>>(flg_p, xcc_p);
  pregemm<<<8192, 256, 0, stream>>>(emb_p, x, wsw_p, bias, pre_p);

  const unsigned short* pre_c = pre_p;
  const unsigned short* ut_c  = ut_p;
  unsigned short* hbc_v = hbc_p;
  float* out_v = out;
  unsigned int* flg_v = flg_p;
  unsigned int* xcc_v = xcc_p;
  void* args[] = {(void*)&pre_c, (void*)&ut_c, (void*)&hbc_v, (void*)&out_v,
                  (void*)&flg_v, (void*)&xcc_v};
  hipLaunchCooperativeKernel((const void*)lstm_kernel, dim3(256), dim3(512), args, 0, stream);
}

// Round 13
// 1153.144 us; speedup vs baseline: 264.8996x; 264.8996x over previous
//
#include <hip/hip_runtime.h>

typedef __attribute__((ext_vector_type(8))) short bf16x8;
typedef __attribute__((ext_vector_type(4))) float f32x4;

// ---- sizes ----
// B=128, T=256, EMB=512, H=1024, 4H=4096, VOC=32000
// out layout: [128][256][1024] f32, then hT [128][1024], then cT [128][1024]

__device__ __forceinline__ unsigned short f2bf(float f) {
  unsigned int u = __builtin_bit_cast(unsigned int, f);
  u = (u + 0x7FFFu + ((u >> 16) & 1u)) >> 16;  // RNE
  return (unsigned short)u;
}
__device__ __forceinline__ float bf2f(unsigned short s) {
  unsigned int u = ((unsigned int)s) << 16;
  return __builtin_bit_cast(float, u);
}
__device__ __forceinline__ void gload_lds16(const void* g, void* l) {
  __builtin_amdgcn_global_load_lds(
      (const __attribute__((address_space(1))) void*)g,
      (__attribute__((address_space(3))) void*)l, 16, 0, 0);
}
__device__ __forceinline__ float sigm(float x) { return 1.0f / (1.0f + __expf(-x)); }
__device__ __forceinline__ float tanh_f(float x) {
  float e = __expf(2.0f * x);
  return 1.0f - 2.0f / (e + 1.0f);  // saturates correctly, no NaN at +-inf
}

// device-coherent (agent-scope) 16B h load as two 8B atomic loads -- PROVEN path
__device__ __forceinline__ bf16x8 loadh16(const unsigned short* p) {
  unsigned long long* q = (unsigned long long*)p;
  unsigned long long lo = __hip_atomic_load(q, __ATOMIC_RELAXED, __HIP_MEMORY_SCOPE_AGENT);
  unsigned long long hi = __hip_atomic_load(q + 1, __ATOMIC_RELAXED, __HIP_MEMORY_SCOPE_AGENT);
  union { unsigned long long u[2]; bf16x8 v; } c;
  c.u[0] = lo; c.u[1] = hi;
  return c.v;
}

// ---------------- f32 -> bf16 elementwise (emb table) ----------------
__global__ void cvt_bf16_vec(const float4* __restrict__ in, ushort4* __restrict__ out, int n4) {
  int i = blockIdx.x * blockDim.x + threadIdx.x;
  int stride = gridDim.x * blockDim.x;
  for (; i < n4; i += stride) {
    float4 v = in[i];
    ushort4 o;
    o.x = f2bf(v.x); o.y = f2bf(v.y); o.z = f2bf(v.z); o.w = f2bf(v.w);
    out[i] = o;
  }
}

// ---- transpose f32 [K][N] -> bf16 [N][K]; SWZ: bake 16B-slot XOR swizzle ----
template <int SWZ>
__global__ void transpose_cvt(const float* __restrict__ in, unsigned short* __restrict__ out,
                              int K, int N) {
  __shared__ float tile[64][65];
  int k0 = blockIdx.x * 64, n0 = blockIdx.y * 64;
  int tid = threadIdx.x;
  int c = tid & 63, rq = tid >> 6;
#pragma unroll
  for (int rr = 0; rr < 16; ++rr) {
    int r = rr * 4 + rq;
    tile[r][c] = in[(size_t)(k0 + r) * N + n0 + c];
  }
  __syncthreads();
#pragma unroll
  for (int ww = 0; ww < 16; ++ww) {
    int nl = ww * 4 + rq;
    int n = n0 + nl;
    int kd = c;
    int ksrc;
    if (SWZ) {
      int s = kd >> 3, e = kd & 7;
      ksrc = ((((s ^ (n & 7)) & 7)) << 3) | e;
    } else {
      ksrc = kd;
    }
    out[(size_t)n * K + k0 + kd] = f2bf(tile[ksrc][nl]);
  }
}

// ---------------- pre = gather(emb,x) @ W + b   -> bf16 [32768][4096] ----------------
__global__ __launch_bounds__(256) void pregemm(
    const unsigned short* __restrict__ emb_bf, const int* __restrict__ x,
    const unsigned short* __restrict__ W_sw, const float* __restrict__ bias,
    unsigned short* __restrict__ pre) {
  __shared__ __align__(16) unsigned short A_lds[2][8192];  // 128 rows x 64 k (swizzled slots)
  __shared__ __align__(16) unsigned short B_lds[2][8192];
  int bid = blockIdx.x;
  int mtile = bid >> 5, ntile = bid & 31;  // 256 x 32
  int tid = threadIdx.x, wv = tid >> 6, ln = tid & 63;

  int xrow[4];
#pragma unroll
  for (int i = 0; i < 4; ++i) {
    int chunk = wv * 4 + i;
    int r = chunk * 8 + (ln >> 3);
    xrow[i] = x[mtile * 128 + r];
  }

  auto stage = [&](int buf, int kb) {
    int k0 = kb * 64;
#pragma unroll
    for (int i = 0; i < 4; ++i) {
      int chunk = wv * 4 + i;
      int r = chunk * 8 + (ln >> 3);
      const unsigned short* srcA =
          emb_bf + (size_t)xrow[i] * 512 + k0 + (((ln & 7) ^ (r & 7)) << 3);
      gload_lds16(srcA, &A_lds[buf][chunk * 512]);
      const unsigned short* srcB =
          W_sw + (size_t)(ntile * 128 + r) * 512 + k0 + ((ln & 7) << 3);
      gload_lds16(srcB, &B_lds[buf][chunk * 512]);
    }
  };

  f32x4 acc[4][4];
#pragma unroll
  for (int i = 0; i < 4; ++i)
#pragma unroll
    for (int j = 0; j < 4; ++j) acc[i][j] = (f32x4)0.0f;

  int wm = wv >> 1, wn = wv & 1;
  stage(0, 0);
#pragma unroll 1
  for (int kb = 0; kb < 8; ++kb) {
    __syncthreads();
    if (kb < 7) stage((kb + 1) & 1, kb + 1);
    int buf = kb & 1;
#pragma unroll
    for (int ks = 0; ks < 2; ++ks) {
      bf16x8 a[4], b[4];
#pragma unroll
      for (int f = 0; f < 4; ++f) {
        int r = wm * 64 + f * 16 + (ln & 15);
        int sa = ((ks * 4 + (ln >> 4)) ^ (r & 7)) & 7;
        a[f] = *(const bf16x8*)&A_lds[buf][r * 64 + sa * 8];
        int n = wn * 64 + f * 16 + (ln & 15);
        int sb = ((ks * 4 + (ln >> 4)) ^ (n & 7)) & 7;
        b[f] = *(const bf16x8*)&B_lds[buf][n * 64 + sb * 8];
      }
#pragma unroll
      for (int i = 0; i < 4; ++i)
#pragma unroll
        for (int j = 0; j < 4; ++j)
          acc[i][j] = __builtin_amdgcn_mfma_f32_16x16x32_bf16(a[i], b[j], acc[i][j], 0, 0, 0);
    }
  }
#pragma unroll
  for (int fm = 0; fm < 4; ++fm) {
#pragma unroll
    for (int fn = 0; fn < 4; ++fn) {
      int n = ntile * 128 + wn * 64 + fn * 16 + (ln & 15);
      float bn = bias[n];
      int m0 = mtile * 128 + wm * 64 + fm * 16 + ((ln >> 4) << 2);
#pragma unroll
      for (int i = 0; i < 4; ++i) {
        pre[(size_t)(m0 + i) * 4096 + n] = f2bf(acc[fm][fn][i] + bn);
      }
    }
  }
}

// ---------------- flag init (256 flags, each on its own 64B line) ----------------
__global__ void init_flags(unsigned int* f) {
  int i = blockIdx.x * blockDim.x + threadIdx.x;  // 4096 dwords = 16 KB
  __hip_atomic_store(&f[i], 0u, __ATOMIC_RELAXED, __HIP_MEMORY_SCOPE_AGENT);
}

// ---------------- persistent LSTM recurrence ----------------
// grid 256 = 8 batch-groups (16 rows) x 32 j-slices (32 hidden cols); 512 thr = 8 waves.
// PROVEN r11 protocol (agent-only hbc/flags; line-spread per-WG flags; per-wave fine
// poll of 4 producers; explicit per-thread vmcnt(0) release drain + barrier + tid0
// flag) with two publish-path deltas (r12's sc0 experiment is reverted -- sc1 stores
// do NOT refresh stale same-XCD L2 lines; cross-scope produce/consume is unsound):
//  (1) shuffle-pack publish: lanes j..j+3 of a row are adjacent wave lanes; 3
//      __shfl_down assemble 4 bf16 in-register; lanes (tid&3)==0 store 8B each.
//      hpack LDS buffer and SYNC2a are DELETED. zbuf WAR: gates' zbuf reads(t)
//      precede SYNC2b(t); zbuf writes(t+1) follow it. Sound with single zbuf.
//  (2) contiguous per-WG h blocks: hbc[parity][(bg*32+js)*512 + row*32 + col].
//      Producer store offset = tid (shorts). Consumer wave reads 4 contiguous 1KB
//      blocks (one per kk-producer js'=4wv+kk), 16B/lane coalesced. Same data and
//      fragment mapping, same summation order -> bit-identical numerics.
__global__ __launch_bounds__(512, 2) void lstm_kernel(
    const unsigned short* __restrict__ pre, const unsigned short* __restrict__ U_t,
    unsigned short* __restrict__ hbc, float* __restrict__ out, unsigned int* flags) {
  __shared__ float zbuf[8][16][132];  // [wave slice][row][z-col], padded
  int bid = blockIdx.x;
  int bg = bid >> 5, js = bid & 31;
  int tid = threadIdx.x, wv = tid >> 6, ln = tid & 63;

  // resident B fragments: ub[gate][kk][cg]; col = gate*1024 + js*32 + cg*16 + (ln&15)
  bf16x8 ub[4][4][2];
#pragma unroll
  for (int g = 0; g < 4; ++g)
#pragma unroll
    for (int kk = 0; kk < 4; ++kk)
#pragma unroll
      for (int cg = 0; cg < 2; ++cg) {
        int col = g * 1024 + js * 32 + cg * 16 + (ln & 15);
        int k = wv * 128 + kk * 32 + ((ln >> 4) << 3);
        ub[g][kk][cg] = *(const bf16x8*)&U_t[(size_t)col * 1024 + k];
      }

  // gate-phase ownership: 512 threads = 16 rows x 32 j
  int row = tid >> 5, j = tid & 31;
  int b = bg * 16 + row;
  int hcol = js * 32 + j;
  float c_state = 0.0f;
  size_t preb = ((size_t)b * 256) * 4096 + (size_t)(js * 32 + j);
  size_t outb = ((size_t)b * 256) * 1024 + (size_t)hcol;
  // consumer: per-kk producer block base (shorts); block js' = 4wv+kk is 512 shorts
  size_t hrd = ((size_t)(bg * 32 + (wv << 2)) << 9) + ((ln & 15) << 5) + ((ln >> 4) << 3);
  // producer: contiguous block, offset = tid shorts (lanes tid&3==0 store 8B)
  size_t hst = ((size_t)(bg * 32 + js) << 9) + (size_t)tid;
  // one flag per 64B line; consumer wave wv's producers: js' in {4wv..4wv+3}
  const unsigned int* flp = flags + ((bg * 32 + (wv << 2) + (ln & 3)) << 4);
  unsigned int* myflag = flags + ((bg * 32 + js) << 4);

  // prefetch pre[t=0]
  float z0n, z1n, z2n, z3n;
  {
    const unsigned short* pp = pre + preb;
    z0n = bf2f(pp[0]); z1n = bf2f(pp[1024]); z2n = bf2f(pp[2048]); z3n = bf2f(pp[3072]);
  }

#pragma unroll 1
  for (int t = 0; t < 256; ++t) {
    int p = t & 1;
    if (t > 0) {
      // per-wave: wait for this wave's 4 producer WGs to publish h_{t-1}
      int guard = 0;
      while (!__all((int)(__hip_atomic_load(flp, __ATOMIC_RELAXED,
                                            __HIP_MEMORY_SCOPE_AGENT) >= (unsigned)t))) {
        if (++guard > 4000000) break;  // watchdog: fail fast+visibly, never hang
        __builtin_amdgcn_s_sleep(1);
      }
      // compiler memory barrier: h loads below must NOT be hoisted above the poll
      asm volatile("" ::: "memory");
      const unsigned short* hp = hbc + (size_t)(p ^ 1) * 131072 + hrd;
      bf16x8 a[4];
#pragma unroll
      for (int kk = 0; kk < 4; ++kk) a[kk] = loadh16(hp + ((size_t)kk << 9));
      f32x4 acc[4][2];
#pragma unroll
      for (int g = 0; g < 4; ++g)
#pragma unroll
        for (int cg = 0; cg < 2; ++cg) acc[g][cg] = (f32x4)0.0f;
#pragma unroll
      for (int kk = 0; kk < 4; ++kk) {
#pragma unroll
        for (int g = 0; g < 4; ++g)
#pragma unroll
          for (int cg = 0; cg < 2; ++cg)
            acc[g][cg] = __builtin_amdgcn_mfma_f32_16x16x32_bf16(a[kk], ub[g][kk][cg],
                                                                 acc[g][cg], 0, 0, 0);
      }
      // private-slice zbuf writes (conflict-free, r11 layout)
#pragma unroll
      for (int g = 0; g < 4; ++g)
#pragma unroll
        for (int cg = 0; cg < 2; ++cg)
#pragma unroll
          for (int i = 0; i < 4; ++i)
            zbuf[wv][((ln >> 4) << 2) + i][g * 32 + cg * 16 + (ln & 15)] = acc[g][cg][i];
      __syncthreads();  // SYNC1: all z slices visible; joins all waves' polls
    }
    // gates (Keras order i,f,c,o) from prefetched pre values
    float z0 = z0n, z1 = z1n, z2 = z2n, z3 = z3n;
    if (t > 0) {
      float s0 = 0.f, s1 = 0.f, s2 = 0.f, s3 = 0.f;
#pragma unroll
      for (int s = 0; s < 8; ++s) {
        s0 += zbuf[s][row][j];
        s1 += zbuf[s][row][32 + j];
        s2 += zbuf[s][row][64 + j];
        s3 += zbuf[s][row][96 + j];
      }
      z0 += s0; z1 += s1; z2 += s2; z3 += s3;
    }
    float ig = sigm(z0), fg = sigm(z1), gg = tanh_f(z2), og = sigm(z3);
    c_state = fg * c_state + ig * gg;
    float h = og * tanh_f(c_state);
    if (t == 255) {
      out[outb + (size_t)t * 1024] = h;
      out[33554432 + (size_t)b * 1024 + hcol] = h;
      out[33554432 + 131072 + (size_t)b * 1024 + hcol] = c_state;
    } else {
      // shuffle-pack publish: lanes j..j+3 (same row, adjacent lanes) -> one 8B store
      float h1 = __shfl_down(h, 1);
      float h2 = __shfl_down(h, 2);
      float h3 = __shfl_down(h, 3);
      if ((tid & 3) == 0) {
        union { unsigned short s[4]; unsigned long long u; } w;
        w.s[0] = f2bf(h); w.s[1] = f2bf(h1); w.s[2] = f2bf(h2); w.s[3] = f2bf(h3);
        __hip_atomic_store((unsigned long long*)&hbc[(size_t)p * 131072 + hst], w.u,
                           __ATOMIC_RELAXED, __HIP_MEMORY_SCOPE_AGENT);
      }
      // EXPLICIT release drain: every wave waits for its own h-stores to reach the
      // coherence point BEFORE the barrier; the flag store after the barrier is then
      // ordered after ALL waves' h-stores. Also orders zbuf reads(t) vs writes(t+1).
      asm volatile("s_waitcnt vmcnt(0)" ::: "memory");
      __syncthreads();  // SYNC2
      if (tid == 0)
        __hip_atomic_store(myflag, (unsigned)(t + 1), __ATOMIC_RELAXED,
                           __HIP_MEMORY_SCOPE_AGENT);
      // bulk out store + next-step prefetch AFTER the publish: off the release path
      out[outb + (size_t)t * 1024] = h;
      const unsigned short* pp = pre + preb + (size_t)(t + 1) * 4096;
      z0n = bf2f(pp[0]); z1n = bf2f(pp[1024]); z2n = bf2f(pp[2048]); z3n = bf2f(pp[3072]);
    }
  }
}

// ---------------- launcher ----------------
extern "C" void kernel_launch(void* const* d_in, const int* in_sizes, int n_in,
                              void* d_out, int out_size, void* d_ws, size_t ws_size,
                              hipStream_t stream) {
  const int*   x    = (const int*)d_in[0];
  // d_in[1] = hidden (ignored by reference module)
  const float* emb  = (const float*)d_in[2];
  const float* W    = (const float*)d_in[3];
  const float* U    = (const float*)d_in[4];
  const float* bias = (const float*)d_in[5];
  float* out = (float*)d_out;

  // workspace layout (bytes) -- dedicated agent-only hbc/flags regions
  const size_t OFS_PRE = 0;                     // 32768*4096*2 = 268435456
  const size_t OFS_EMB = 268435456;             // 32000*512*2  = 32768000
  const size_t OFS_WSW = 301203456;             // 4096*512*2   = 4194304
  const size_t OFS_UT  = 305397760;             // 4096*1024*2  = 8388608
  const size_t OFS_HBC = 313786368;             // 2*128*1024*2 = 524288
  const size_t OFS_FLG = 314310656;             // 256 * 64B    = 16384
  const size_t WS_NEED = 314327040;
  if (ws_size < WS_NEED) return;  // insufficient scratch -> fail validation visibly

  char* ws = (char*)d_ws;
  unsigned short* pre_p = (unsigned short*)(ws + OFS_PRE);
  unsigned short* emb_p = (unsigned short*)(ws + OFS_EMB);
  unsigned short* wsw_p = (unsigned short*)(ws + OFS_WSW);
  unsigned short* ut_p  = (unsigned short*)(ws + OFS_UT);
  unsigned short* hbc_p = (unsigned short*)(ws + OFS_HBC);
  unsigned int*   flg_p = (unsigned int*)(ws + OFS_FLG);

  cvt_bf16_vec<<<2048, 256, 0, stream>>>((const float4*)emb, (ushort4*)emb_p, 4096000);
  transpose_cvt<1><<<dim3(8, 64), 256, 0, stream>>>(W, wsw_p, 512, 4096);
  transpose_cvt<0><<<dim3(16, 64), 256, 0, stream>>>(U, ut_p, 1024, 4096);
  init_flags<<<16, 256, 0, stream>>>(flg_p);
  pregemm<<<8192, 256, 0, stream>>>(emb_p, x, wsw_p, bias, pre_p);

  const unsigned short* pre_c = pre_p;
  const unsigned short* ut_c  = ut_p;
  unsigned short* hbc_v = hbc_p;
  float* out_v = out;
  unsigned int* flg_v = flg_p;
  void* args[] = {(void*)&pre_c, (void*)&ut_c, (void*)&hbc_v, (void*)&out_v, (void*)&flg_v};
  hipLaunchCooperativeKernel((const void*)lstm_kernel, dim3(256), dim3(512), args, 0, stream);
}